// Round 6
// baseline (225.394 us; speedup 1.0000x reference)
//
#include <hip/hip_runtime.h>
#include <math.h>

typedef __attribute__((ext_vector_type(8))) short s16x8;
typedef __attribute__((ext_vector_type(4))) float f32x4;

__device__ __forceinline__ float b2f(unsigned short u) {
    unsigned int x = ((unsigned int)u) << 16;
    float f; __builtin_memcpy(&f, &x, 4); return f;
}
__device__ __forceinline__ unsigned short f2b(float f) {
    unsigned int x; __builtin_memcpy(&x, &f, 4);
    unsigned int r = x + 0x7FFFu + ((x >> 16) & 1u);
    return (unsigned short)(r >> 16);
}

// async global->LDS, 16B per lane, linear LDS dest (guide §5 / m97)
#define GLDS(g, l) __builtin_amdgcn_global_load_lds( \
    (const __attribute__((address_space(1))) unsigned int*)(g), \
    (__attribute__((address_space(3))) unsigned int*)(l), 16, 0, 0)

__device__ __forceinline__ float blk_reduce_sum(float v, float* red) {
    int tid = threadIdx.x;
    red[tid] = v; __syncthreads();
    for (int off = 128; off > 0; off >>= 1) {
        if (tid < off) red[tid] += red[tid + off];
        __syncthreads();
    }
    float r = red[0]; __syncthreads();
    return r;
}

// ---------- prep: x [b][c][t] fp32 -> xT [b][t][c] bf16 ----------
__global__ __launch_bounds__(256) void txp_x(const float* __restrict__ x,
                                             unsigned short* __restrict__ xT) {
    __shared__ float t[32][33];
    int tt = blockIdx.x, ct = blockIdx.y, b = blockIdx.z;
    int col = threadIdx.x & 31, rq = threadIdx.x >> 5;
    const float* xb = x + (((size_t)b * 256 + ct * 32) << 10) + (tt << 5);
#pragma unroll
    for (int p = 0; p < 4; ++p) { int r = rq + p * 8; t[r][col] = xb[((size_t)r << 10) + col]; }
    __syncthreads();
    unsigned short* o = xT + ((size_t)b << 18) + ((size_t)(tt << 5) << 8) + (ct << 5);
#pragma unroll
    for (int p = 0; p < 4; ++p) { int tr = rq + p * 8; o[((size_t)tr << 8) + col] = f2b(t[col][tr]); }
}

// ---------- prep: Wq/Wk/Wv [c][k] fp32 -> WT [k][c] bf16 (3 matrices) ----------
__global__ __launch_bounds__(256) void txp_w(const float* __restrict__ Wq, const float* __restrict__ Wk,
                                             const float* __restrict__ Wv, unsigned short* __restrict__ WT) {
    __shared__ float t[32][33];
    int kt = blockIdx.x, ct = blockIdx.y, z = blockIdx.z;
    const float* W = (z == 0) ? Wq : (z == 1) ? Wk : Wv;
    int col = threadIdx.x & 31, rq = threadIdx.x >> 5;
    const float* wb = W + ((ct * 32) << 8) + (kt << 5);
#pragma unroll
    for (int p = 0; p < 4; ++p) { int r = rq + p * 8; t[r][col] = wb[(r << 8) + col]; }
    __syncthreads();
    unsigned short* o = WT + (z << 16) + ((kt << 5) << 8) + (ct << 5);
#pragma unroll
    for (int p = 0; p < 4; ++p) { int tr = rq + p * 8; o[(tr << 8) + col] = f2b(t[col][tr]); }
}

// ---------- prep: weight-norm both conv weights -> wK [kk][o][ci] bf16 (merged) ----------
__global__ __launch_bounds__(256) void wnorm_k(const float* __restrict__ v1, const float* __restrict__ g1,
                                               unsigned short* __restrict__ w1K,
                                               const float* __restrict__ v2, const float* __restrict__ g2,
                                               unsigned short* __restrict__ w2K) {
    __shared__ float red[256];
    int o = blockIdx.x & 255, tid = threadIdx.x;
    const float* v = (blockIdx.x >= 256) ? v2 : v1;
    const float* g = (blockIdx.x >= 256) ? g2 : g1;
    unsigned short* wK = (blockIdx.x >= 256) ? w2K : w1K;
    float a0 = v[o * 768 + tid * 3 + 0];
    float a1 = v[o * 768 + tid * 3 + 1];
    float a2 = v[o * 768 + tid * 3 + 2];
    float tot = blk_reduce_sum(a0 * a0 + a1 * a1 + a2 * a2, red);
    float sc = g[o] / sqrtf(tot);
    wK[0 * 65536 + o * 256 + tid] = f2b(a0 * sc);
    wK[1 * 65536 + o * 256 + tid] = f2b(a1 * sc);
    wK[2 * 65536 + o * 256 + tid] = f2b(a2 * sc);
}

// ---------- init: zero conv pad rows + colD ----------
__global__ void init_k(unsigned short* attT, unsigned short* h1T, float* colD) {
    int idx = blockIdx.x * 256 + threadIdx.x;   // grid 64 -> 16384
    colD[idx] = 0.f;
    if (idx < 8192) {
        int b = idx >> 9, r = idx & 511;
        attT[(size_t)b * 262656 + r] = 0;
        h1T[(size_t)b * 262656 + r] = 0;
    }
}

// ---------- generic bf16 MFMA GEMM: C = A . B^T  (A [M][K], B [N][K], K-contiguous) ----------
// 128x128 tile, 4 waves (2x2). 2-phase double-buffered pipeline (T3-min):
//   STAGE(next -> buf^1); ds_read+MFMA on buf[cur]; vmcnt(0); s_barrier.
// MODE 0: q AND k proj (mt>=8 -> k), out bf16 [t][256]+bias[col]
// MODE 1: v proj     out vT bf16 [c][1024]+bias[row]
// MODE 2: scores     out E = exp(qk/16) bf16 [j][1024], masked->0, skip tiles nt>mt;
//                    fused column sums into colD (o32 param) via shfl_xor + atomicAdd
// MODE 3: PV         A=E, B=vTs(=v/colD), K=(mt+1)*128, out attT padded rows;
//                    nt==0 blocks also fuse rowsum[j] = sum_i E[j][i]/colD[i] (bias=colD, o32=rows)
// MODE 4: conv1      A=attT shifted 3 segs, B=w1K, +bias relu, out h1T padded
// MODE 5: conv2      A=h1T shifted, B=w2K, +bias relu, + x*(1+wx), relu, out fp32 [o][t]
template<int MODE>
__global__ __launch_bounds__(256) void gemm_k(const unsigned short* __restrict__ Ab,
                                              const unsigned short* __restrict__ Bb,
                                              unsigned short* __restrict__ o16,
                                              float* __restrict__ o32,
                                              const float* __restrict__ bias,
                                              const float* __restrict__ xres,
                                              const float* __restrict__ wxv, int b0) {
    int nt = blockIdx.x, mt = blockIdx.y, bz = blockIdx.z;
    if constexpr (MODE == 2) { if (nt > mt) return; }
    bool isk = false;
    if constexpr (MODE == 0) { isk = (mt >= 8); mt &= 7; }
    int b = b0 + bz;
    int m0 = mt << 7, n0 = nt << 7;
    constexpr int LDA = (MODE == 3) ? 1024 : 256;
    constexpr int LDB = (MODE == 3) ? 1024 : 256;
    const unsigned short* A;
    const unsigned short* B;
    unsigned short* OB = o16;
    const float* BI = bias;
    if constexpr (MODE == 0)      { A = Ab + ((size_t)b << 18);
                                    B = isk ? Bb + 65536 : Bb;
                                    if (isk) { OB = (unsigned short*)o32; BI = xres; } }
    else if constexpr (MODE == 1) { A = Ab;                      B = Bb + ((size_t)b << 18); }
    else if constexpr (MODE == 2) { A = Ab + ((size_t)b << 18); B = Bb + ((size_t)b << 18); }
    else if constexpr (MODE == 3) { A = Ab + ((size_t)bz << 20); B = Bb + ((size_t)b << 18); }
    else                          { A = Ab + (size_t)b * 262656; B = Bb; }

    int tid = threadIdx.x;
    int wid = tid >> 6, lane = tid & 63;
    int wr = wid >> 1, wc = wid & 1;
    int lrow = lane & 15, koct = lane >> 4;
    int srow = tid >> 2, scol = (tid & 3) << 3;   // staging: row 0..63, col-group

    __shared__ short As[2][128 * 32];
    __shared__ short Bs[2][128 * 32];
    __shared__ float Rs[(MODE == 3) ? 1024 : 1];

    int ksteps = (MODE == 3) ? ((mt + 1) << 2) : 8;
    constexpr int NSEG = (MODE >= 4) ? 3 : 1;
    int total = NSEG * ksteps;

    if constexpr (MODE == 3) {
        if (nt == 0)
            for (int i = tid; i < (ksteps << 5); i += 256)
                Rs[i] = 1.f / bias[(b << 10) + i];
    }
    float racc = 0.f;

    f32x4 acc[4][4];
#pragma unroll
    for (int m = 0; m < 4; ++m)
#pragma unroll
        for (int n = 0; n < 4; ++n) acc[m][n] = (f32x4){0.f, 0.f, 0.f, 0.f};

    // stage step s into LDS buffer bufi
    auto stage_to = [&](int s, int bufi) {
        const unsigned short *ga, *gb;
        if constexpr (MODE >= 4) {
            int seg = s >> 3, k0 = (s & 7) << 5;
            ga = A + (size_t)(m0 + seg + srow) * 256 + k0 + scol;
            gb = B + (seg << 16) + (size_t)(n0 + srow) * 256 + k0 + scol;
        } else {
            int k0 = s << 5;
            ga = A + (size_t)(m0 + srow) * LDA + k0 + scol;
            gb = B + (size_t)(n0 + srow) * LDB + k0 + scol;
        }
        short* as = &As[bufi][0];
        short* bs = &Bs[bufi][0];
        GLDS(ga,                    &as[tid << 3]);
        GLDS(ga + (size_t)64 * LDA, &as[(tid << 3) + 2048]);
        GLDS(gb,                    &bs[tid << 3]);
        GLDS(gb + (size_t)64 * LDB, &bs[(tid << 3) + 2048]);
    };

    // prologue
    stage_to(0, 0);
    asm volatile("s_waitcnt vmcnt(0)" ::: "memory");
    __builtin_amdgcn_s_barrier();

    int cur = 0;
    for (int s = 0; s < total; ++s) {
        if (s + 1 < total) stage_to(s + 1, cur ^ 1);   // loads fly during compute
        const short* as = &As[cur][0];
        const short* bs = &Bs[cur][0];
        s16x8 af[4], bf[4];
#pragma unroll
        for (int m = 0; m < 4; ++m)
            af[m] = *(const s16x8*)&as[(wr * 64 + m * 16 + lrow) * 32 + (koct << 3)];
#pragma unroll
        for (int n = 0; n < 4; ++n)
            bf[n] = *(const s16x8*)&bs[(wc * 64 + n * 16 + lrow) * 32 + (koct << 3)];
#pragma unroll
        for (int m = 0; m < 4; ++m)
#pragma unroll
            for (int n = 0; n < 4; ++n)
                acc[m][n] = __builtin_amdgcn_mfma_f32_16x16x32_bf16(af[m], bf[n], acc[m][n], 0, 0, 0);
        if constexpr (MODE == 3) {
            if (nt == 0) {   // fused rowsum from the LDS-resident E tile
                int k0 = s << 5;
                int rrow = tid >> 1, rh = (tid & 1) << 4;
                s16x8 e0 = *(const s16x8*)&as[rrow * 32 + rh];
                s16x8 e1 = *(const s16x8*)&as[rrow * 32 + rh + 8];
#pragma unroll
                for (int c = 0; c < 8; ++c) racc += b2f((unsigned short)e0[c]) * Rs[k0 + rh + c];
#pragma unroll
                for (int c = 0; c < 8; ++c) racc += b2f((unsigned short)e1[c]) * Rs[k0 + rh + 8 + c];
            }
        }
        if (s + 1 < total) {
            asm volatile("s_waitcnt vmcnt(0)" ::: "memory");
            __builtin_amdgcn_s_barrier();
        }
        cur ^= 1;
    }

    if constexpr (MODE == 3) {
        if (nt == 0) {
            float other = __shfl_xor(racc, 1, 64);
            if ((tid & 1) == 0) o32[(b << 10) + (mt << 7) + (tid >> 1)] = racc + other;
        }
    }

    int rb = m0 + wr * 64 + koct * 4;
    int cb = n0 + wc * 64 + lrow;

    if constexpr (MODE == 2) {
        float csum[4] = {0.f, 0.f, 0.f, 0.f};
#pragma unroll
        for (int m = 0; m < 4; ++m) {
#pragma unroll
            for (int n = 0; n < 4; ++n) {
                int col = cb + n * 16;
#pragma unroll
                for (int j = 0; j < 4; ++j) {
                    int row = rb + m * 16 + j;
                    float e = (col <= row) ? expf(acc[m][n][j] * 0.0625f) : 0.f;
                    o16[((size_t)bz << 20) + ((size_t)row << 10) + col] = f2b(e);
                    csum[n] += e;
                }
            }
        }
#pragma unroll
        for (int n = 0; n < 4; ++n) {   // reduce across koct lane groups, one atomic per col
            float v = csum[n];
            v += __shfl_xor(v, 16, 64);
            v += __shfl_xor(v, 32, 64);
            if (koct == 0) atomicAdd(&o32[(b << 10) + cb + n * 16], v);
        }
        return;
    }

#pragma unroll
    for (int m = 0; m < 4; ++m) {
#pragma unroll
        for (int n = 0; n < 4; ++n) {
            int col = cb + n * 16;
#pragma unroll
            for (int j = 0; j < 4; ++j) {
                int row = rb + m * 16 + j;
                float v = acc[m][n][j];
                if constexpr (MODE == 0) {
                    OB[((size_t)b << 18) + ((size_t)row << 8) + col] = f2b(v + BI[col]);
                } else if constexpr (MODE == 1) {
                    o16[((size_t)b << 18) + ((size_t)row << 10) + col] = f2b(v + BI[row]);
                } else if constexpr (MODE == 3) {
                    o16[(size_t)b * 262656 + ((size_t)(row + 2) << 8) + col] = f2b(v);
                } else if constexpr (MODE == 4) {
                    o16[(size_t)b * 262656 + ((size_t)(row + 2) << 8) + col] =
                        f2b(fmaxf(v + BI[col], 0.f));
                } else if constexpr (MODE == 5) {
                    size_t oi = (((size_t)(b << 8) + col) << 10) + row;
                    float h = fmaxf(v + BI[col], 0.f);
                    h = fmaxf(h + xres[oi] * (1.f + wxv[(b << 10) + row]), 0.f);
                    o32[oi] = h;
                }
            }
        }
    }
}

// ---------- vTs = vT / colD (in place, per key index i) ----------
__global__ __launch_bounds__(256) void vscale_k(unsigned short* __restrict__ vT,
                                                const float* __restrict__ colD, int b0) {
    int c = blockIdx.x, bz = blockIdx.y, b = b0 + bz;
    int tid = threadIdx.x;
    unsigned short* row = vT + ((size_t)b << 18) + ((size_t)c << 10);
    ushort4 v4 = *(const ushort4*)&row[tid << 2];
    float4 d4 = ((const float4*)(colD + (b << 10)))[tid];
    ushort4 o;
    o.x = f2b(b2f(v4.x) / d4.x);
    o.y = f2b(b2f(v4.y) / d4.y);
    o.z = f2b(b2f(v4.z) / d4.z);
    o.w = f2b(b2f(v4.w) / d4.w);
    *(ushort4*)&row[tid << 2] = o;
}

// ---------- weight_x[b][t] = softmax_t(rowsum) ----------
__global__ __launch_bounds__(256) void wx_k(const float* __restrict__ rowsum, float* __restrict__ wx) {
    int b = blockIdx.x, tid = threadIdx.x;
    __shared__ float red[256];
    float4 r4 = ((const float4*)(rowsum + ((size_t)b << 10)))[tid];
    float mx = fmaxf(fmaxf(r4.x, r4.y), fmaxf(r4.z, r4.w));
    red[tid] = mx; __syncthreads();
    for (int off = 128; off > 0; off >>= 1) {
        if (tid < off) red[tid] = fmaxf(red[tid], red[tid + off]);
        __syncthreads();
    }
    float M = red[0]; __syncthreads();
    float e0 = expf(r4.x - M), e1 = expf(r4.y - M), e2 = expf(r4.z - M), e3 = expf(r4.w - M);
    float Z = blk_reduce_sum(e0 + e1 + e2 + e3, red);
    float4 o = make_float4(e0 / Z, e1 / Z, e2 / Z, e3 / Z);
    ((float4*)(wx + ((size_t)b << 10)))[tid] = o;
}

extern "C" void kernel_launch(void* const* d_in, const int* in_sizes, int n_in,
                              void* d_out, int out_size, void* d_ws, size_t ws_size,
                              hipStream_t stream) {
    const float* x   = (const float*)d_in[0];
    const float* Wq  = (const float*)d_in[1];
    const float* bq  = (const float*)d_in[2];
    const float* Wk  = (const float*)d_in[3];
    const float* bk  = (const float*)d_in[4];
    const float* Wv  = (const float*)d_in[5];
    const float* bv  = (const float*)d_in[6];
    const float* c1v = (const float*)d_in[7];
    const float* c1g = (const float*)d_in[8];
    const float* c1b = (const float*)d_in[9];
    const float* c2v = (const float*)d_in[10];
    const float* c2g = (const float*)d_in[11];
    const float* c2b = (const float*)d_in[12];
    float* out = (float*)d_out;

    // ws layout in BYTES (all regions disjoint)
    char* w = (char*)d_ws;
    unsigned short* xT   = (unsigned short*)(w + 0);          // 8,388,608
    unsigned short* qb   = (unsigned short*)(w + 8388608);    // 8,388,608
    unsigned short* kb   = (unsigned short*)(w + 16777216);   // 8,388,608
    unsigned short* vT   = (unsigned short*)(w + 25165824);   // 8,388,608
    unsigned short* WT   = (unsigned short*)(w + 33554432);   //   393,216
    unsigned short* w1K  = (unsigned short*)(w + 33947648);   //   393,216
    unsigned short* w2K  = (unsigned short*)(w + 34340864);   //   393,216
    unsigned short* attT = (unsigned short*)(w + 34734080);   // 8,404,992 (1026 rows/b)
    unsigned short* h1T  = (unsigned short*)(w + 43139072);   // 8,404,992
    float* colD = (float*)(w + 51544064);                     //    65,536
    float* rows = (float*)(w + 51675136);                     //    65,536
    float* wxp  = (float*)(w + 51740672);                     //    65,536
    unsigned short* S = (unsigned short*)(w + 51806208);      // nb * 2,097,152

    dim3 blk(256);

    txp_x<<<dim3(32, 8, 16), blk, 0, stream>>>(x, xT);
    txp_w<<<dim3(8, 8, 3), blk, 0, stream>>>(Wq, Wk, Wv, WT);
    wnorm_k<<<dim3(512), blk, 0, stream>>>(c1v, c1g, w1K, c2v, c2g, w2K);
    init_k<<<dim3(64), blk, 0, stream>>>(attT, h1T, colD);

    // q and k in one launch (mt>=8 -> k); v projection
    gemm_k<0><<<dim3(2, 16, 16), blk, 0, stream>>>(xT, WT, qb, (float*)kb, bq, bk, nullptr, 0);
    gemm_k<1><<<dim3(8, 2, 16), blk, 0, stream>>>(WT + 131072, xT, vT, nullptr, bv, nullptr, nullptr, 0);

    // chunk the 2 MB/batch E buffer by available ws (deterministic in ws_size)
    size_t fixed = 51806208;
    size_t avail = (ws_size > fixed) ? ws_size - fixed : 0;
    int bmax = (int)(avail / 2097152);
    if (bmax < 1) bmax = 1;
    if (bmax > 16) bmax = 16;
    for (int b0 = 0; b0 < 16; b0 += bmax) {
        int nb = (16 - b0 < bmax) ? (16 - b0) : bmax;
        gemm_k<2><<<dim3(8, 8, nb), blk, 0, stream>>>(qb, kb, S, colD, nullptr, nullptr, nullptr, b0);
        vscale_k<<<dim3(256, nb), blk, 0, stream>>>(vT, colD, b0);
        gemm_k<3><<<dim3(2, 8, nb), blk, 0, stream>>>(S, vT, attT, rows, colD, nullptr, nullptr, b0);
    }
    wx_k<<<dim3(16), blk, 0, stream>>>(rows, wxp);
    gemm_k<4><<<dim3(2, 8, 16), blk, 0, stream>>>(attT, w1K, h1T, nullptr, c1b, nullptr, nullptr, 0);
    gemm_k<5><<<dim3(2, 8, 16), blk, 0, stream>>>(h1T, w2K, nullptr, out, c2b, x, wxp, 0);
}

// Round 7
// 203.077 us; speedup vs baseline: 1.1099x; 1.1099x over previous
//
#include <hip/hip_runtime.h>
#include <math.h>

typedef __attribute__((ext_vector_type(8))) short s16x8;
typedef __attribute__((ext_vector_type(4))) float f32x4;

__device__ __forceinline__ float b2f(unsigned short u) {
    unsigned int x = ((unsigned int)u) << 16;
    float f; __builtin_memcpy(&f, &x, 4); return f;
}
__device__ __forceinline__ unsigned short f2b(float f) {
    unsigned int x; __builtin_memcpy(&x, &f, 4);
    unsigned int r = x + 0x7FFFu + ((x >> 16) & 1u);
    return (unsigned short)(r >> 16);
}

// async global->LDS, 16B per lane, linear LDS dest (guide §5 / m97)
#define GLDS(g, l) __builtin_amdgcn_global_load_lds( \
    (const __attribute__((address_space(1))) unsigned int*)(g), \
    (__attribute__((address_space(3))) unsigned int*)(l), 16, 0, 0)

// ---------- fused prep: x-transpose, W-transpose, weight-norm, zero-init ----------
// flat grid: [0,4096) txp_x | [4096,4288) txp_w | [4288,4800) wnorm | [4800,4864) init
__global__ __launch_bounds__(256) void prep_k(const float* __restrict__ x, unsigned short* __restrict__ xT,
                                              const float* __restrict__ Wq, const float* __restrict__ Wk,
                                              const float* __restrict__ Wv, unsigned short* __restrict__ WT,
                                              const float* __restrict__ v1, const float* __restrict__ g1,
                                              unsigned short* __restrict__ w1K,
                                              const float* __restrict__ v2, const float* __restrict__ g2,
                                              unsigned short* __restrict__ w2K,
                                              unsigned short* __restrict__ attT, unsigned short* __restrict__ h1T,
                                              float* __restrict__ colD) {
    __shared__ float t[32][33];
    __shared__ float red[256];
    int bid = blockIdx.x, tid = threadIdx.x;
    if (bid < 4096) {               // x [b][c][t] -> xT [b][t][c] bf16
        int tt = bid & 31, ct = (bid >> 5) & 7, b = bid >> 8;
        int col = tid & 31, rq = tid >> 5;
        const float* xb = x + (((size_t)b * 256 + ct * 32) << 10) + (tt << 5);
#pragma unroll
        for (int p = 0; p < 4; ++p) { int r = rq + p * 8; t[r][col] = xb[((size_t)r << 10) + col]; }
        __syncthreads();
        unsigned short* o = xT + ((size_t)b << 18) + ((size_t)(tt << 5) << 8) + (ct << 5);
#pragma unroll
        for (int p = 0; p < 4; ++p) { int tr = rq + p * 8; o[((size_t)tr << 8) + col] = f2b(t[col][tr]); }
    } else if (bid < 4288) {        // W [c][k] -> WT [k][c] bf16 (3 mats)
        int id = bid - 4096;
        int kt = id & 7, ct = (id >> 3) & 7, z = id >> 6;
        const float* W = (z == 0) ? Wq : (z == 1) ? Wk : Wv;
        int col = tid & 31, rq = tid >> 5;
        const float* wb = W + ((ct * 32) << 8) + (kt << 5);
#pragma unroll
        for (int p = 0; p < 4; ++p) { int r = rq + p * 8; t[r][col] = wb[(r << 8) + col]; }
        __syncthreads();
        unsigned short* o = WT + (z << 16) + ((kt << 5) << 8) + (ct << 5);
#pragma unroll
        for (int p = 0; p < 4; ++p) { int tr = rq + p * 8; o[(tr << 8) + col] = f2b(t[col][tr]); }
    } else if (bid < 4800) {        // weight-norm -> wK [kk][o][ci] bf16
        int id = bid - 4288;
        int o = id & 255;
        const float* v = (id >= 256) ? v2 : v1;
        const float* g = (id >= 256) ? g2 : g1;
        unsigned short* wK = (id >= 256) ? w2K : w1K;
        float a0 = v[o * 768 + tid * 3 + 0];
        float a1 = v[o * 768 + tid * 3 + 1];
        float a2 = v[o * 768 + tid * 3 + 2];
        red[tid] = a0 * a0 + a1 * a1 + a2 * a2; __syncthreads();
        for (int off = 128; off > 0; off >>= 1) {
            if (tid < off) red[tid] += red[tid + off];
            __syncthreads();
        }
        float sc = g[o] / sqrtf(red[0]);
        wK[0 * 65536 + o * 256 + tid] = f2b(a0 * sc);
        wK[1 * 65536 + o * 256 + tid] = f2b(a1 * sc);
        wK[2 * 65536 + o * 256 + tid] = f2b(a2 * sc);
    } else {                        // zero pads + colD
        int idx = (bid - 4800) * 256 + tid;  // 0..16383
        colD[idx] = 0.f;
        if (idx < 8192) {
            int b = idx >> 9, r = idx & 511;
            attT[(size_t)b * 262656 + r] = 0;
            h1T[(size_t)b * 262656 + r] = 0;
        }
    }
}

// ---------- generic bf16 MFMA GEMM: C = A . B^T  (A [M][K], B [N][K], K-contiguous) ----------
// 128x128 tile, 512 thr = 8 waves (2M x 4N), each wave 64x32 = 4x2 frags of 16x16x32.
// 2-phase double-buffered: STAGE(next->buf^1); ds_read+MFMA on buf[cur]; vmcnt(0); s_barrier.
// MODE 0: q AND k proj (mt>=8 -> k), out bf16 [t][256]+bias[col]
// MODE 1: v proj     out vT bf16 [c][1024]+bias[row]
// MODE 2: scores     out E = exp(qk/16) bf16 [j][1024], masked->0, skip tiles nt>mt;
//                    fused column sums into colD (o32) via shfl_xor + atomicAdd
// MODE 3: PV         A=E, B=vTs(=v/colD), K=(mt+1)*128, out attT padded rows;
//                    nt==0 blocks fuse rowsum[j]=sum_i E[j][i]/colD[i] (bias=colD, o32=rows)
// MODE 4: conv1      A=attT shifted 3 segs, B=w1K, +bias relu, out h1T padded
// MODE 5: conv2      A=h1T shifted, B=w2K, +bias relu, + x*(1+wx), relu, out fp32 [o][t]
template<int MODE>
__global__ __launch_bounds__(512) void gemm_k(const unsigned short* __restrict__ Ab,
                                              const unsigned short* __restrict__ Bb,
                                              unsigned short* __restrict__ o16,
                                              float* __restrict__ o32,
                                              const float* __restrict__ bias,
                                              const float* __restrict__ xres,
                                              const float* __restrict__ wxv, int b0) {
    int nt = blockIdx.x, mt = blockIdx.y, bz = blockIdx.z;
    if constexpr (MODE == 2) { if (nt > mt) return; }
    bool isk = false;
    if constexpr (MODE == 0) { isk = (mt >= 8); mt &= 7; }
    int b = b0 + bz;
    int m0 = mt << 7, n0 = nt << 7;
    constexpr int LDA = (MODE == 3) ? 1024 : 256;
    constexpr int LDB = (MODE == 3) ? 1024 : 256;
    const unsigned short* A;
    const unsigned short* B;
    unsigned short* OB = o16;
    const float* BI = bias;
    if constexpr (MODE == 0)      { A = Ab + ((size_t)b << 18);
                                    B = isk ? Bb + 65536 : Bb;
                                    if (isk) { OB = (unsigned short*)o32; BI = xres; } }
    else if constexpr (MODE == 1) { A = Ab;                      B = Bb + ((size_t)b << 18); }
    else if constexpr (MODE == 2) { A = Ab + ((size_t)b << 18); B = Bb + ((size_t)b << 18); }
    else if constexpr (MODE == 3) { A = Ab + ((size_t)bz << 20); B = Bb + ((size_t)b << 18); }
    else                          { A = Ab + (size_t)b * 262656; B = Bb; }

    int tid = threadIdx.x;
    int wid = tid >> 6, lane = tid & 63;
    int wr = wid >> 2, wc = wid & 3;            // 2 x 4 waves
    int lrow = lane & 15, koct = lane >> 4;
    int srow = tid >> 2, scol = (tid & 3) << 3; // staging: row 0..127

    __shared__ short As[2][128 * 32];
    __shared__ short Bs[2][128 * 32];
    __shared__ float Rs[(MODE == 3) ? 1024 : 1];

    int ksteps = (MODE == 3) ? ((mt + 1) << 2) : 8;
    constexpr int NSEG = (MODE >= 4) ? 3 : 1;
    int total = NSEG * ksteps;

    if constexpr (MODE == 3) {
        if (nt == 0)
            for (int i = tid; i < (ksteps << 5); i += 512)
                Rs[i] = 1.f / bias[(b << 10) + i];
    }
    float racc = 0.f;

    f32x4 acc[4][2];
#pragma unroll
    for (int m = 0; m < 4; ++m)
#pragma unroll
        for (int n = 0; n < 2; ++n) acc[m][n] = (f32x4){0.f, 0.f, 0.f, 0.f};

    auto stage_to = [&](int s, int bufi) {
        const unsigned short *ga, *gb;
        if constexpr (MODE >= 4) {
            int seg = s >> 3, k0 = (s & 7) << 5;
            ga = A + (size_t)(m0 + seg + srow) * 256 + k0 + scol;
            gb = B + (seg << 16) + (size_t)(n0 + srow) * 256 + k0 + scol;
        } else {
            int k0 = s << 5;
            ga = A + (size_t)(m0 + srow) * LDA + k0 + scol;
            gb = B + (size_t)(n0 + srow) * LDB + k0 + scol;
        }
        GLDS(ga, &As[bufi][tid << 3]);
        GLDS(gb, &Bs[bufi][tid << 3]);
    };

    stage_to(0, 0);
    asm volatile("s_waitcnt vmcnt(0)" ::: "memory");
    __builtin_amdgcn_s_barrier();

    int cur = 0;
    for (int s = 0; s < total; ++s) {
        if (s + 1 < total) stage_to(s + 1, cur ^ 1);
        const short* as = &As[cur][0];
        const short* bs = &Bs[cur][0];
        s16x8 af[4], bf[2];
#pragma unroll
        for (int m = 0; m < 4; ++m)
            af[m] = *(const s16x8*)&as[(wr * 64 + m * 16 + lrow) * 32 + (koct << 3)];
#pragma unroll
        for (int n = 0; n < 2; ++n)
            bf[n] = *(const s16x8*)&bs[(wc * 32 + n * 16 + lrow) * 32 + (koct << 3)];
#pragma unroll
        for (int m = 0; m < 4; ++m)
#pragma unroll
            for (int n = 0; n < 2; ++n)
                acc[m][n] = __builtin_amdgcn_mfma_f32_16x16x32_bf16(af[m], bf[n], acc[m][n], 0, 0, 0);
        if constexpr (MODE == 3) {
            if (nt == 0) {   // fused rowsum from the LDS-resident E tile
                int k0 = s << 5;
                int rrow = tid >> 2, rh = (tid & 3) << 3;
                s16x8 e0 = *(const s16x8*)&as[rrow * 32 + rh];
#pragma unroll
                for (int c = 0; c < 8; ++c) racc += b2f((unsigned short)e0[c]) * Rs[k0 + rh + c];
            }
        }
        if (s + 1 < total) {
            asm volatile("s_waitcnt vmcnt(0)" ::: "memory");
            __builtin_amdgcn_s_barrier();
        }
        cur ^= 1;
    }

    if constexpr (MODE == 3) {
        if (nt == 0) {
            float v = racc;
            v += __shfl_xor(v, 1, 64);
            v += __shfl_xor(v, 2, 64);
            if ((tid & 3) == 0) o32[(b << 10) + (mt << 7) + (tid >> 2)] = v;
        }
    }

    int rb = m0 + wr * 64 + koct * 4;
    int cb = n0 + wc * 32 + lrow;

    if constexpr (MODE == 2) {
        float csum[2] = {0.f, 0.f};
#pragma unroll
        for (int m = 0; m < 4; ++m) {
#pragma unroll
            for (int n = 0; n < 2; ++n) {
                int col = cb + n * 16;
#pragma unroll
                for (int j = 0; j < 4; ++j) {
                    int row = rb + m * 16 + j;
                    float e = (col <= row) ? expf(acc[m][n][j] * 0.0625f) : 0.f;
                    o16[((size_t)bz << 20) + ((size_t)row << 10) + col] = f2b(e);
                    csum[n] += e;
                }
            }
        }
#pragma unroll
        for (int n = 0; n < 2; ++n) {   // reduce across koct groups, one atomic per col
            float v = csum[n];
            v += __shfl_xor(v, 16, 64);
            v += __shfl_xor(v, 32, 64);
            if (koct == 0) atomicAdd(&o32[(b << 10) + cb + n * 16], v);
        }
        return;
    }

#pragma unroll
    for (int m = 0; m < 4; ++m) {
#pragma unroll
        for (int n = 0; n < 2; ++n) {
            int col = cb + n * 16;
#pragma unroll
            for (int j = 0; j < 4; ++j) {
                int row = rb + m * 16 + j;
                float v = acc[m][n][j];
                if constexpr (MODE == 0) {
                    OB[((size_t)b << 18) + ((size_t)row << 8) + col] = f2b(v + BI[col]);
                } else if constexpr (MODE == 1) {
                    o16[((size_t)b << 18) + ((size_t)row << 10) + col] = f2b(v + BI[row]);
                } else if constexpr (MODE == 3) {
                    o16[(size_t)b * 262656 + ((size_t)(row + 2) << 8) + col] = f2b(v);
                } else if constexpr (MODE == 4) {
                    o16[(size_t)b * 262656 + ((size_t)(row + 2) << 8) + col] =
                        f2b(fmaxf(v + BI[col], 0.f));
                } else if constexpr (MODE == 5) {
                    size_t oi = (((size_t)(b << 8) + col) << 10) + row;
                    float h = fmaxf(v + BI[col], 0.f);
                    h = fmaxf(h + xres[oi] * (1.f + wxv[(b << 10) + row]), 0.f);
                    o32[oi] = h;
                }
            }
        }
    }
}

// ---------- vTs = vT / colD (in place, per key index i) ----------
__global__ __launch_bounds__(256) void vscale_k(unsigned short* __restrict__ vT,
                                                const float* __restrict__ colD, int b0) {
    int c = blockIdx.x, bz = blockIdx.y, b = b0 + bz;
    int tid = threadIdx.x;
    unsigned short* row = vT + ((size_t)b << 18) + ((size_t)c << 10);
    ushort4 v4 = *(const ushort4*)&row[tid << 2];
    float4 d4 = ((const float4*)(colD + (b << 10)))[tid];
    ushort4 o;
    o.x = f2b(b2f(v4.x) / d4.x);
    o.y = f2b(b2f(v4.y) / d4.y);
    o.z = f2b(b2f(v4.z) / d4.z);
    o.w = f2b(b2f(v4.w) / d4.w);
    *(ushort4*)&row[tid << 2] = o;
}

// ---------- weight_x[b][t] = softmax_t(rowsum) ----------
__global__ __launch_bounds__(256) void wx_k(const float* __restrict__ rowsum, float* __restrict__ wx) {
    int b = blockIdx.x, tid = threadIdx.x;
    __shared__ float red[256];
    float4 r4 = ((const float4*)(rowsum + ((size_t)b << 10)))[tid];
    float mx = fmaxf(fmaxf(r4.x, r4.y), fmaxf(r4.z, r4.w));
    red[tid] = mx; __syncthreads();
    for (int off = 128; off > 0; off >>= 1) {
        if (tid < off) red[tid] = fmaxf(red[tid], red[tid + off]);
        __syncthreads();
    }
    float M = red[0]; __syncthreads();
    float e0 = expf(r4.x - M), e1 = expf(r4.y - M), e2 = expf(r4.z - M), e3 = expf(r4.w - M);
    red[tid] = e0 + e1 + e2 + e3; __syncthreads();
    for (int off = 128; off > 0; off >>= 1) {
        if (tid < off) red[tid] += red[tid + off];
        __syncthreads();
    }
    float Z = red[0];
    float4 o = make_float4(e0 / Z, e1 / Z, e2 / Z, e3 / Z);
    ((float4*)(wx + ((size_t)b << 10)))[tid] = o;
}

extern "C" void kernel_launch(void* const* d_in, const int* in_sizes, int n_in,
                              void* d_out, int out_size, void* d_ws, size_t ws_size,
                              hipStream_t stream) {
    const float* x   = (const float*)d_in[0];
    const float* Wq  = (const float*)d_in[1];
    const float* bq  = (const float*)d_in[2];
    const float* Wk  = (const float*)d_in[3];
    const float* bk  = (const float*)d_in[4];
    const float* Wv  = (const float*)d_in[5];
    const float* bv  = (const float*)d_in[6];
    const float* c1v = (const float*)d_in[7];
    const float* c1g = (const float*)d_in[8];
    const float* c1b = (const float*)d_in[9];
    const float* c2v = (const float*)d_in[10];
    const float* c2g = (const float*)d_in[11];
    const float* c2b = (const float*)d_in[12];
    float* out = (float*)d_out;

    // ws layout in BYTES (all regions disjoint)
    char* w = (char*)d_ws;
    unsigned short* xT   = (unsigned short*)(w + 0);          // 8,388,608
    unsigned short* qb   = (unsigned short*)(w + 8388608);    // 8,388,608
    unsigned short* kb   = (unsigned short*)(w + 16777216);   // 8,388,608
    unsigned short* vT   = (unsigned short*)(w + 25165824);   // 8,388,608
    unsigned short* WT   = (unsigned short*)(w + 33554432);   //   393,216
    unsigned short* w1K  = (unsigned short*)(w + 33947648);   //   393,216
    unsigned short* w2K  = (unsigned short*)(w + 34340864);   //   393,216
    unsigned short* attT = (unsigned short*)(w + 34734080);   // 8,404,992 (1026 rows/b)
    unsigned short* h1T  = (unsigned short*)(w + 43139072);   // 8,404,992
    float* colD = (float*)(w + 51544064);                     //    65,536
    float* rows = (float*)(w + 51675136);                     //    65,536
    float* wxp  = (float*)(w + 51740672);                     //    65,536
    unsigned short* S = (unsigned short*)(w + 51806208);      // nb * 2,097,152

    dim3 blk(256), blk2(512);

    prep_k<<<dim3(4864), blk, 0, stream>>>(x, xT, Wq, Wk, Wv, WT,
                                           c1v, c1g, w1K, c2v, c2g, w2K,
                                           attT, h1T, colD);

    // q and k in one launch (mt>=8 -> k); v projection
    gemm_k<0><<<dim3(2, 16, 16), blk2, 0, stream>>>(xT, WT, qb, (float*)kb, bq, bk, nullptr, 0);
    gemm_k<1><<<dim3(8, 2, 16), blk2, 0, stream>>>(WT + 131072, xT, vT, nullptr, bv, nullptr, nullptr, 0);

    // chunk the 2 MB/batch E buffer by available ws (deterministic in ws_size)
    size_t fixed = 51806208;
    size_t avail = (ws_size > fixed) ? ws_size - fixed : 0;
    int bmax = (int)(avail / 2097152);
    if (bmax < 1) bmax = 1;
    if (bmax > 16) bmax = 16;
    for (int b0 = 0; b0 < 16; b0 += bmax) {
        int nb = (16 - b0 < bmax) ? (16 - b0) : bmax;
        gemm_k<2><<<dim3(8, 8, nb), blk2, 0, stream>>>(qb, kb, S, colD, nullptr, nullptr, nullptr, b0);
        vscale_k<<<dim3(256, nb), blk, 0, stream>>>(vT, colD, b0);
        gemm_k<3><<<dim3(2, 8, nb), blk2, 0, stream>>>(S, vT, attT, rows, colD, nullptr, nullptr, b0);
    }
    wx_k<<<dim3(16), blk, 0, stream>>>(rows, wxp);
    gemm_k<4><<<dim3(2, 8, 16), blk2, 0, stream>>>(attT, w1K, h1T, nullptr, c1b, nullptr, nullptr, 0);
    gemm_k<5><<<dim3(2, 8, 16), blk2, 0, stream>>>(h1T, w2K, nullptr, out, c2b, x, wxp, 0);
}